// Round 5
// baseline (154.312 us; speedup 1.0000x reference)
//
#include <hip/hip_runtime.h>

#define TT 8192
#define CIN 512
#define COUT 512
#define NB 8
#define KTOT 1536   // 3 * CIN
#define NT 24       // K tiles of 64

typedef __attribute__((ext_vector_type(4))) float f32x4;
typedef __attribute__((ext_vector_type(16))) float f32x16;
typedef __attribute__((ext_vector_type(8))) short bf16x8;
typedef __attribute__((ext_vector_type(8))) unsigned short u16x8;

#define GLD16(g, l) __builtin_amdgcn_global_load_lds(                      \
    (const __attribute__((address_space(1))) void*)(g),                    \
    (__attribute__((address_space(3))) void*)(l), 16, 0, 0)

#define CFENCE() asm volatile("" ::: "memory")
#define SBAR() do { CFENCE(); __builtin_amdgcn_s_barrier(); CFENCE(); } while (0)
#define VMCNT4() asm volatile("s_waitcnt vmcnt(4)" ::: "memory")
#define VMCNT0() asm volatile("s_waitcnt vmcnt(0)" ::: "memory")
#define MFMA(a_, b_, c_) __builtin_amdgcn_mfma_f32_16x16x32_bf16((a_), (b_), (c_), 0, 0, 0)
#define MFMA32(a_, b_, c_) __builtin_amdgcn_mfma_f32_32x32x16_bf16((a_), (b_), (c_), 0, 0, 0)

__device__ inline unsigned short f2bf(float f) {
  union { float f; unsigned int u; } v; v.f = f;
  unsigned int u = v.u;
  unsigned int r = (u + 0x7FFFu + ((u >> 16) & 1u)) >> 16;  // RNE
  return (unsigned short)r;
}

__global__ void k_convert_w(const float* __restrict__ W0, const float* __restrict__ W1,
                            const float* __restrict__ W2, unsigned short* __restrict__ Wb) {
  int i = blockIdx.x * 256 + threadIdx.x;
  if (i >= COUT * CIN) return;
  const float* Ws = blockIdx.y == 0 ? W0 : (blockIdx.y == 1 ? W1 : W2);
  int o = i >> 9, c = i & 511;
  Wb[(size_t)o * KTOT + blockIdx.y * CIN + c] = f2bf(Ws[i]);
}

// x (B, C, T) fp32 -> xbT (T, C) bf16 per batch. grid (T/64, C/64, nb), block 256
__global__ void k_transpose(const float* __restrict__ x, unsigned short* __restrict__ xbT,
                            int b_base) {
  int b = b_base + blockIdx.z;
  const float* xb = x + (size_t)b * CIN * TT;
  unsigned short* xo = xbT + (size_t)blockIdx.z * TT * CIN;
  __shared__ float tile[64][65];
  int t0 = blockIdx.x * 64, c0 = blockIdx.y * 64;
  int tid = threadIdx.x;
#pragma unroll
  for (int it = 0; it < 16; ++it) {
    int L = it * 256 + tid;
    int c = L >> 6, t = L & 63;
    tile[c][t] = xb[(size_t)(c0 + c) * TT + (t0 + t)];
  }
  __syncthreads();
#pragma unroll
  for (int it = 0; it < 16; ++it) {
    int L = it * 256 + tid;
    int t = L >> 6, c = L & 63;
    xo[(size_t)(t0 + t) * CIN + (c0 + c)] = f2bf(tile[c][t]);
  }
}

// ---------------- 256x256 fused gather-GEMM, 32x32x16 MFMA ----------------
// grid (TT/256, COUT/256, NB), block 512 (8 waves, 2M x 4N)
__global__ __launch_bounds__(512) void k_gemm256(
    const unsigned short* __restrict__ Wb, const unsigned short* __restrict__ xbT,
    const float* __restrict__ d, const float* __restrict__ bias,
    float* __restrict__ out) {
  __shared__ __align__(16) unsigned short As[2][256 * 64];
  __shared__ __align__(16) unsigned short Bs[2][256 * 64];
  const int b = blockIdx.z;
  const unsigned short* xb = xbT + (size_t)b * TT * CIN;
  const int t0 = blockIdx.x * 256;
  const int row0 = blockIdx.y * 256;
  const int tid = threadIdx.x;
  const int lane = tid & 63, wid = tid >> 6;
  const int wr = wid >> 2, wc = wid & 3;
  const int l31 = lane & 31, lh = lane >> 5;

  // staging sources: round j covers row r = j*64 + (tid>>3), chunk slot tid&7
  const int srow = tid >> 3;
  const int cSrc8 = (((tid & 7) ^ ((tid >> 4) & 7))) * 8;  // swizzled 16B chunk (ushorts)
  int aOff[4];        // Wb ushort offsets, add tc*64
  int bOff[3][4];     // xbT ushort offsets per segment, add (tc&7)*64
#pragma unroll
  for (int j = 0; j < 4; ++j) {
    int r = j * 64 + srow;
    aOff[j] = (row0 + r) * KTOT + cSrc8;
    int t = t0 + r;
    float dv = d[(size_t)b * TT + t];
    int dil = (int)dv; if (dil < 1) dil = 1;
    int p = t - dil; if (p < 0) p = -p; p &= (TT - 1);
    int f0 = t + dil;
    int f = (f0 >= TT) ? (TT - 1 - (f0 & (TT - 1))) : f0;
    bOff[0][j] = p * CIN + cSrc8;
    bOff[1][j] = t * CIN + cSrc8;
    bOff[2][j] = f * CIN + cSrc8;
  }

  // fragment read offsets: row r = base + l31, global chunk c = ks*2 + lh,
  // LDS slot = c ^ ((r>>1)&7); base mult of 32 -> s7 = (l31>>1)&7
  const int s7 = (l31 >> 1) & 7;
  int ckv[4];
#pragma unroll
  for (int ks = 0; ks < 4; ++ks) ckv[ks] = ((ks * 2 + lh) ^ s7) * 8;
  int aR[4], bR[2];
#pragma unroll
  for (int m = 0; m < 4; ++m) aR[m] = (wr * 128 + m * 32 + l31) * 64;
#pragma unroll
  for (int n = 0; n < 2; ++n) bR[n] = (wc * 64 + n * 32 + l31) * 64;

#define STAGE_A2(tc_, buf_, jp_) do {                                         \
    _Pragma("unroll") for (int j = 2 * (jp_); j < 2 * (jp_) + 2; ++j)         \
      GLD16(Wb + aOff[j] + (tc_) * 64, &As[buf_][j * 4096 + wid * 512]);      \
  } while (0)
#define STAGE_B2(tc_, buf_, jp_) do {                                         \
    _Pragma("unroll") for (int j = 2 * (jp_); j < 2 * (jp_) + 2; ++j)         \
      GLD16(xb + bOff[(tc_) >> 3][j] + ((tc_) & 7) * 64,                      \
            &Bs[buf_][j * 4096 + wid * 512]);                                 \
  } while (0)

  // prologue: A(0)->A[0], B(0)->B[0], B(1)->B[1]; keep B(1) in flight
  STAGE_A2(0, 0, 0); STAGE_A2(0, 0, 1);
  STAGE_B2(0, 0, 0); STAGE_B2(0, 0, 1);
  STAGE_B2(1, 1, 0); STAGE_B2(1, 1, 1);
  VMCNT4();
  SBAR();

  bf16x8 af[4][4], bf0[4], bf1[4];
  f32x16 acc[4][2] = {};

  // per tile: stage A(tc+1) at PH0/PH1 (L2-hot), B(tc+2) at PH3 (HBM-cold).
#pragma unroll 2
  for (int tc = 0; tc < NT; ++tc) {
    const int cur = tc & 1;
    // ---------- PH0: read af[0..1][*] + bf0[*]; stage A(tc+1) jp0; MFMA Q(0,0)
#pragma unroll
    for (int m = 0; m < 2; ++m)
#pragma unroll
      for (int ks = 0; ks < 4; ++ks)
        af[m][ks] = *(const bf16x8*)&As[cur][aR[m] + ckv[ks]];
#pragma unroll
    for (int ks = 0; ks < 4; ++ks)
      bf0[ks] = *(const bf16x8*)&Bs[cur][bR[0] + ckv[ks]];
    if (tc + 1 < NT) STAGE_A2(tc + 1, cur ^ 1, 0);
    SBAR();
    __builtin_amdgcn_s_setprio(1);
#pragma unroll
    for (int m = 0; m < 2; ++m)
#pragma unroll
      for (int ks = 0; ks < 4; ++ks)
        acc[m][0] = MFMA32(af[m][ks], bf0[ks], acc[m][0]);
    __builtin_amdgcn_s_setprio(0);
    SBAR();
    // ---------- PH1: read af[2..3][*]; stage A(tc+1) jp1; MFMA Q(1,0)
#pragma unroll
    for (int m = 2; m < 4; ++m)
#pragma unroll
      for (int ks = 0; ks < 4; ++ks)
        af[m][ks] = *(const bf16x8*)&As[cur][aR[m] + ckv[ks]];
    if (tc + 1 < NT) STAGE_A2(tc + 1, cur ^ 1, 1);
    SBAR();
    __builtin_amdgcn_s_setprio(1);
#pragma unroll
    for (int m = 2; m < 4; ++m)
#pragma unroll
      for (int ks = 0; ks < 4; ++ks)
        acc[m][0] = MFMA32(af[m][ks], bf0[ks], acc[m][0]);
    __builtin_amdgcn_s_setprio(0);
    // ---------- PH2: read bf1[*]; barrier (publishes B[cur] fully read); MFMA Q(0,1)
#pragma unroll
    for (int ks = 0; ks < 4; ++ks)
      bf1[ks] = *(const bf16x8*)&Bs[cur][bR[1] + ckv[ks]];
    SBAR();
    __builtin_amdgcn_s_setprio(1);
#pragma unroll
    for (int m = 0; m < 2; ++m)
#pragma unroll
      for (int ks = 0; ks < 4; ++ks)
        acc[m][1] = MFMA32(af[m][ks], bf1[ks], acc[m][1]);
    __builtin_amdgcn_s_setprio(0);
    // ---------- PH3: stage B(tc+2) into B[cur] (safe after PH2 barrier); MFMA Q(1,1)
    if (tc + 2 < NT) { STAGE_B2(tc + 2, cur, 0); STAGE_B2(tc + 2, cur, 1); }
    __builtin_amdgcn_s_setprio(1);
#pragma unroll
    for (int m = 2; m < 4; ++m)
#pragma unroll
      for (int ks = 0; ks < 4; ++ks)
        acc[m][1] = MFMA32(af[m][ks], bf1[ks], acc[m][1]);
    __builtin_amdgcn_s_setprio(0);
    if (tc + 2 < NT) { VMCNT4(); }        // keep B(tc+2) in flight
    else if (tc + 1 < NT) { VMCNT0(); }   // tail: drain for last tile
    SBAR();
  }

  // epilogue: bias + fp32 store. 32x32 C/D: col=lane&31, row=(reg&3)+8*(reg>>2)+4*lh
  float* ob = out + (size_t)b * COUT * TT;
#pragma unroll
  for (int m = 0; m < 4; ++m) {
    int m0 = row0 + wr * 128 + m * 32;
#pragma unroll
    for (int n = 0; n < 2; ++n) {
      int t = t0 + wc * 64 + n * 32 + l31;
      f32x16 v = acc[m][n];
#pragma unroll
      for (int q = 0; q < 4; ++q)
#pragma unroll
        for (int j = 0; j < 4; ++j) {
          int row = m0 + q * 8 + lh * 4 + j;
          ob[(size_t)row * TT + t] = v[q * 4 + j] + bias[row];
        }
    }
  }
}

// ---------------- fallback 128x128 (small ws) ----------------
__global__ __launch_bounds__(256) void k_gemm(
    const unsigned short* __restrict__ Wb, const unsigned short* __restrict__ xbT,
    const float* __restrict__ d, const float* __restrict__ bias,
    float* __restrict__ out, int b_base) {
  __shared__ __align__(16) unsigned short As[128 * 32];
  __shared__ __align__(16) unsigned short Bs[128 * 32];
  int b = b_base + blockIdx.z;
  const unsigned short* xb = xbT + (size_t)blockIdx.z * TT * CIN;
  int row0 = blockIdx.x * 128;
  int t0 = blockIdx.y * 128;
  int tid = threadIdx.x;
  int lane = tid & 63, wid = tid >> 6;
  int wr = wid >> 1, wc = wid & 1;
  int l15 = lane & 15, kg = lane >> 4;
  int rs = tid >> 2, cch = tid & 3;

  const unsigned short* aw[2];
  const unsigned short* bw[2][3];
#pragma unroll
  for (int h = 0; h < 2; ++h) {
    int r = rs + h * 64;
    int cs = cch ^ ((r >> 1) & 3);
    aw[h] = Wb + (size_t)(row0 + r) * KTOT + cs * 8;
    int t = t0 + r;
    float dv = d[(size_t)b * TT + t];
    int dil = (int)dv; if (dil < 1) dil = 1;
    int p = t - dil; if (p < 0) p = -p; p &= (TT - 1);
    int f0 = t + dil;
    int f = (f0 >= TT) ? (TT - 1 - (f0 & (TT - 1))) : f0;
    bw[h][0] = xb + (size_t)p * CIN + cs * 8;
    bw[h][1] = xb + (size_t)t * CIN + cs * 8;
    bw[h][2] = xb + (size_t)f * CIN + cs * 8;
  }
  unsigned short* aDst[2];
  unsigned short* bDst[2];
#pragma unroll
  for (int h = 0; h < 2; ++h) {
    aDst[h] = As + h * 2048 + wid * 512;
    bDst[h] = Bs + h * 2048 + wid * 512;
  }
  int aoff[4], boff[4];
#pragma unroll
  for (int mi = 0; mi < 4; ++mi) {
    int r = wr * 64 + mi * 16 + l15;
    aoff[mi] = r * 32 + (kg ^ ((r >> 1) & 3)) * 8;
  }
#pragma unroll
  for (int ni = 0; ni < 4; ++ni) {
    int r = wc * 64 + ni * 16 + l15;
    boff[ni] = r * 32 + (kg ^ ((r >> 1) & 3)) * 8;
  }
  f32x4 acc[4][4] = {};
#pragma unroll
  for (int s = 0; s < 3; ++s) {
    for (int kt = 0; kt < 16; ++kt) {
      int koff = kt * 32;
#pragma unroll
      for (int h = 0; h < 2; ++h) {
        GLD16(aw[h] + s * CIN + koff, aDst[h]);
        GLD16(bw[h][s] + koff, bDst[h]);
      }
      __syncthreads();
      bf16x8 af[4], bf[4];
#pragma unroll
      for (int mi = 0; mi < 4; ++mi) af[mi] = *(const bf16x8*)(&As[aoff[mi]]);
#pragma unroll
      for (int ni = 0; ni < 4; ++ni) bf[ni] = *(const bf16x8*)(&Bs[boff[ni]]);
#pragma unroll
      for (int mi = 0; mi < 4; ++mi)
#pragma unroll
        for (int ni = 0; ni < 4; ++ni)
          acc[mi][ni] = MFMA(af[mi], bf[ni], acc[mi][ni]);
      __syncthreads();
    }
  }
  float* ob = out + (size_t)b * COUT * TT;
#pragma unroll
  for (int mi = 0; mi < 4; ++mi) {
    int m0 = row0 + wr * 64 + mi * 16 + kg * 4;
#pragma unroll
    for (int ni = 0; ni < 4; ++ni) {
      int t = t0 + wc * 64 + ni * 16 + l15;
#pragma unroll
      for (int j = 0; j < 4; ++j) {
        ob[(size_t)(m0 + j) * TT + t] = acc[mi][ni][j] + bias[m0 + j];
      }
    }
  }
}

extern "C" void kernel_launch(void* const* d_in, const int* in_sizes, int n_in,
                              void* d_out, int out_size, void* d_ws, size_t ws_size,
                              hipStream_t stream) {
  const float* x  = (const float*)d_in[0];
  const float* d  = (const float*)d_in[1];
  const float* W0 = (const float*)d_in[2];
  const float* b0 = (const float*)d_in[3];
  const float* W1 = (const float*)d_in[4];
  const float* W2 = (const float*)d_in[5];
  float* out = (float*)d_out;

  char* ws = (char*)d_ws;
  unsigned short* Wb  = (unsigned short*)ws;                       // 1.5 MiB
  unsigned short* xbT = (unsigned short*)(ws + (2u << 20));        // 8 MiB per batch
  const size_t SZ_XBT1 = (size_t)TT * CIN * 2;
  const size_t NEED_FULL = (size_t)(2u << 20) + (size_t)NB * SZ_XBT1;  // ~66 MiB
  const size_t NEED_MIN  = (size_t)(2u << 20) + SZ_XBT1;               // ~10 MiB

  if (ws_size >= NEED_MIN) {
    k_convert_w<<<dim3(1024, 3), 256, 0, stream>>>(W0, W1, W2, Wb);
    if (ws_size >= NEED_FULL) {
      k_transpose<<<dim3(TT / 64, CIN / 64, NB), 256, 0, stream>>>(x, xbT, 0);
      k_gemm256<<<dim3(TT / 256, COUT / 256, NB), 512, 0, stream>>>(Wb, xbT, d, b0, out);
    } else {
      for (int b = 0; b < NB; ++b) {
        k_transpose<<<dim3(TT / 64, CIN / 64, 1), 256, 0, stream>>>(x, xbT, b);
        k_gemm<<<dim3(COUT / 128, TT / 128, 1), 256, 0, stream>>>(Wb, xbT, d, b0, out, b);
      }
    }
  } else {
    for (int b = 0; b < NB; ++b) {
      k_transpose<<<dim3(TT / 64, CIN / 64, 1), 256, 0, stream>>>(x, xbT, b);
      k_gemm<<<dim3(COUT / 128, TT / 128, 1), 256, 0, stream>>>(Wb, xbT, d, b0, out, b);
    }
  }
}